// Round 1
// baseline (123.986 us; speedup 1.0000x reference)
//
#include <hip/hip_runtime.h>
#include <stdint.h>

// Problem constants (fixed by setup_inputs): B=32, N=512, D=512
#define BATCH 32
#define NDIM 512
#define DDIM 512
#define XELEMS (BATCH * NDIM * DDIM)   // 8388608
#define WELEMS (DDIM * DDIM)           // 262144

typedef _Float16 f16x8 __attribute__((ext_vector_type(8)));
typedef _Float16 f16x4v __attribute__((ext_vector_type(4)));
typedef float f32x4 __attribute__((ext_vector_type(4)));

// --- async global -> LDS, 16 bytes per lane (global_load_lds_dwordx4) ---
// LDS destination semantics: wave-uniform base + lane*16 (guide §5 caveat).
__device__ __forceinline__ void gl_lds16(const _Float16* g, _Float16* l) {
    __builtin_amdgcn_global_load_lds(
        (const __attribute__((address_space(1))) unsigned int*)(g),
        (__attribute__((address_space(3))) unsigned int*)(l),
        16, 0, 0);
}

// ---------------- pass 0a: X fp32 -> fp16 ----------------
__global__ __launch_bounds__(256) void convert_x(const float4* __restrict__ X4,
                                                 f16x4v* __restrict__ Xh4) {
    int i = blockIdx.x * 256 + threadIdx.x;   // grid sized exactly: XELEMS/4 threads
    float4 v = X4[i];
    f16x4v o;
    o.x = (_Float16)v.x;
    o.y = (_Float16)v.y;
    o.z = (_Float16)v.z;
    o.w = (_Float16)v.w;
    Xh4[i] = o;
}

// ---------------- pass 0b: W fp32 -> Wt fp16 (Wt[e][d] = W[d][e]) ----------------
__global__ __launch_bounds__(256) void transpose_w(const float* __restrict__ W,
                                                   _Float16* __restrict__ Wt) {
    __shared__ float tile[32][33];   // +1 pad breaks bank conflicts
    int bx = blockIdx.x;             // e-tile
    int by = blockIdx.y;             // d-tile
    int tx = threadIdx.x & 31;
    int ty = threadIdx.x >> 5;       // 0..7
    for (int r = ty; r < 32; r += 8)
        tile[r][tx] = W[(by * 32 + r) * DDIM + bx * 32 + tx];
    __syncthreads();
    for (int r = ty; r < 32; r += 8)
        Wt[(size_t)(bx * 32 + r) * DDIM + by * 32 + tx] = (_Float16)tile[tx][r];
}

// ---------------- shared GEMM body: C = A @ Bt^T  (both row-major, K-contiguous) ----
// BM=BN=128, BK=64, 256 threads = 4 waves, each wave: 2x8 grid of 16x16x32 MFMA.
// EPI==0: store fp16 Y.  EPI==1: fp32 out + bias, zero diagonal, batched via blockIdx.z.
template <int EPI>
__global__ __launch_bounds__(256) void gemm_bt(const _Float16* __restrict__ A,
                                               const _Float16* __restrict__ Bt,
                                               _Float16* __restrict__ Yout,
                                               float* __restrict__ Sout,
                                               const float* __restrict__ bias_ptr) {
    __shared__ __align__(16) _Float16 As[128 * 64];
    __shared__ __align__(16) _Float16 Bs[128 * 64];

    const int tid  = threadIdx.x;
    const int lane = tid & 63;
    const int wv   = tid >> 6;        // 0..3

    const int m0 = blockIdx.y * 128;
    const int n0 = blockIdx.x * 128;
    const int batch = blockIdx.z;

    const _Float16* Ab = A;
    const _Float16* Bb = Bt;
    if (EPI == 1) {
        Ab = A  + (size_t)batch * (NDIM * DDIM);
        Bb = Bt + (size_t)batch * (NDIM * DDIM);
    }

    // staging decomposition: per wave-issue, 64 lanes x 16B = 8 rows of 64 fp16
    const int lr = lane >> 3;         // row within 8-row chunk
    const int lk = (lane & 7) * 8;    // fp16 col offset (16B granules)

    const int quad = lane >> 4;       // 0..3
    const int l16  = lane & 15;

    f32x4 acc[2][8];
#pragma unroll
    for (int i = 0; i < 2; ++i)
#pragma unroll
        for (int j = 0; j < 8; ++j)
            acc[i][j] = (f32x4){0.f, 0.f, 0.f, 0.f};

    for (int k0 = 0; k0 < DDIM; k0 += 64) {
        // ---- stage A,B tiles: 16 wave-issues each of 1KB; wave w owns chunks w*4..w*4+3
#pragma unroll
        for (int t = 0; t < 4; ++t) {
            int chunk = wv * 4 + t;            // 0..15
            int row   = chunk * 8 + lr;        // 0..127
            gl_lds16(Ab + (size_t)(m0 + row) * DDIM + k0 + lk, &As[chunk * 512]);
            gl_lds16(Bb + (size_t)(n0 + row) * DDIM + k0 + lk, &Bs[chunk * 512]);
        }
        __syncthreads();   // drains vmcnt (global_load_lds) + lgkm

        // ---- compute: 2 K-steps of 32
#pragma unroll
        for (int kk = 0; kk < 64; kk += 32) {
            f16x8 a0 = *(const f16x8*)&As[(wv * 32 +      l16) * 64 + kk + quad * 8];
            f16x8 a1 = *(const f16x8*)&As[(wv * 32 + 16 + l16) * 64 + kk + quad * 8];
#pragma unroll
            for (int nt = 0; nt < 8; ++nt) {
                f16x8 b = *(const f16x8*)&Bs[(nt * 16 + l16) * 64 + kk + quad * 8];
                acc[0][nt] = __builtin_amdgcn_mfma_f32_16x16x32_f16(a0, b, acc[0][nt], 0, 0, 0);
                acc[1][nt] = __builtin_amdgcn_mfma_f32_16x16x32_f16(a1, b, acc[1][nt], 0, 0, 0);
            }
        }
        __syncthreads();
    }

    // ---- epilogue. C/D layout: col = lane&15, row = quad*4 + reg (m89/m91-verified)
    float bias = (EPI == 1) ? bias_ptr[0] : 0.f;
#pragma unroll
    for (int mt = 0; mt < 2; ++mt) {
#pragma unroll
        for (int nt = 0; nt < 8; ++nt) {
#pragma unroll
            for (int r = 0; r < 4; ++r) {
                int gi = m0 + wv * 32 + mt * 16 + quad * 4 + r;
                int gj = n0 + nt * 16 + l16;
                float v = acc[mt][nt][r];
                if (EPI == 0) {
                    Yout[(size_t)gi * DDIM + gj] = (_Float16)v;
                } else {
                    v += bias;
                    if (gi == gj) v = 0.f;
                    Sout[((size_t)batch * NDIM + gi) * NDIM + gj] = v;
                }
            }
        }
    }
}

extern "C" void kernel_launch(void* const* d_in, const int* in_sizes, int n_in,
                              void* d_out, int out_size, void* d_ws, size_t ws_size,
                              hipStream_t stream) {
    const float* X  = (const float*)d_in[0];   // (32, 512, 512) fp32
    const float* W  = (const float*)d_in[1];   // (512, 512) fp32
    const float* bp = (const float*)d_in[2];   // scalar fp32
    float* out = (float*)d_out;                // (32, 512, 512) fp32

    // workspace layout (fp16): Xh[8388608] | Wt[262144] | Y[8388608]  = 34,078,720 B
    _Float16* Xh = (_Float16*)d_ws;
    _Float16* Wt = Xh + XELEMS;
    _Float16* Y  = Wt + WELEMS;

    // pass 0: dtype conversion (+ W transpose so both GEMMs are A @ Bt^T)
    convert_x<<<XELEMS / 4 / 256, 256, 0, stream>>>((const float4*)X, (f16x4v*)Xh);
    transpose_w<<<dim3(16, 16), 256, 0, stream>>>(W, Wt);

    // pass 1: Y = Xflat(16384x512) @ Wt^T   -> fp16 Y
    gemm_bt<0><<<dim3(4, 128, 1), 256, 0, stream>>>(Xh, Wt, Y, nullptr, nullptr);

    // pass 2: S_b = Y_b(512x512) @ X_b^T  + bias, diag=0 -> fp32 out
    gemm_bt<1><<<dim3(4, 4, BATCH), 256, 0, stream>>>(Y, Xh, nullptr, out, bp);

    (void)in_sizes; (void)n_in; (void)out_size; (void)ws_size;
}

// Round 2
// 119.585 us; speedup vs baseline: 1.0368x; 1.0368x over previous
//
#include <hip/hip_runtime.h>
#include <stdint.h>

// Problem constants (fixed by setup_inputs): B=32, N=512, D=512
#define BATCH 32
#define NDIM 512
#define DDIM 512
#define XELEMS (BATCH * NDIM * DDIM)   // 8388608
#define WELEMS (DDIM * DDIM)           // 262144

typedef _Float16 f16x8 __attribute__((ext_vector_type(8)));
typedef _Float16 f16x4v __attribute__((ext_vector_type(4)));
typedef float f32x4 __attribute__((ext_vector_type(4)));

// --- async global -> LDS, 16 bytes per lane (global_load_lds_dwordx4) ---
// LDS dest is wave-uniform base + lane*16 (guide §5 caveat) — layout is pinned,
// so bank-conflict avoidance is done by permuting the GLOBAL source per lane.
__device__ __forceinline__ void gl_lds16(const _Float16* g, _Float16* l) {
    __builtin_amdgcn_global_load_lds(
        (const __attribute__((address_space(1))) unsigned int*)(g),
        (__attribute__((address_space(3))) unsigned int*)(l),
        16, 0, 0);
}

// ---------------- pass 0: X fp32->fp16 convert  +  W fp32->fp16 transpose ----------
// blocks [0, 8192): convert;  blocks [8192, 8448): transpose (32x32 tiles).
__global__ __launch_bounds__(256) void prep(const float4* __restrict__ X4,
                                            f16x4v* __restrict__ Xh4,
                                            const float* __restrict__ W,
                                            _Float16* __restrict__ Wt) {
    __shared__ float tile[32][33];   // +1 pad breaks bank conflicts (transpose path)
    int bid = blockIdx.x;
    if (bid < XELEMS / 4 / 256) {
        int i = bid * 256 + threadIdx.x;
        float4 v = X4[i];
        f16x4v o;
        o.x = (_Float16)v.x;
        o.y = (_Float16)v.y;
        o.z = (_Float16)v.z;
        o.w = (_Float16)v.w;
        Xh4[i] = o;
    } else {
        int t = bid - XELEMS / 4 / 256;   // 0..255
        int bx = t & 15;                  // e-tile
        int by = t >> 4;                  // d-tile
        int tx = threadIdx.x & 31;
        int ty = threadIdx.x >> 5;        // 0..7
        for (int r = ty; r < 32; r += 8)
            tile[r][tx] = W[(by * 32 + r) * DDIM + bx * 32 + tx];
        __syncthreads();
        for (int r = ty; r < 32; r += 8)
            Wt[(size_t)(bx * 32 + r) * DDIM + by * 32 + tx] = (_Float16)tile[tx][r];
    }
}

// ---------------- shared GEMM body: C = A @ Bt^T  (both row-major, K-contiguous) ----
// BM=BN=128, BK=64, 256 threads = 4 waves, each wave: 2x8 grid of 16x16x32 MFMA.
// LDS layout XOR-swizzled: logical k-chunk c of row r lives at physical chunk
// c ^ (r & 7). Fragment-read banks then fan across all 32 banks (2-way = free)
// instead of the 16-way conflict of the unswizzled 128B-row-stride layout.
// EPI==0: store fp16 Y.  EPI==1: fp32 out + bias, zero diagonal, batched via blockIdx.z.
template <int EPI>
__global__ __launch_bounds__(256) void gemm_bt(const _Float16* __restrict__ A,
                                               const _Float16* __restrict__ Bt,
                                               _Float16* __restrict__ Yout,
                                               float* __restrict__ Sout,
                                               const float* __restrict__ bias_ptr) {
    __shared__ __align__(16) _Float16 As[128 * 64];
    __shared__ __align__(16) _Float16 Bs[128 * 64];

    const int tid  = threadIdx.x;
    const int lane = tid & 63;
    const int wv   = tid >> 6;        // 0..3

    const int m0 = blockIdx.y * 128;
    const int n0 = blockIdx.x * 128;
    const int batch = blockIdx.z;

    const _Float16* Ab = A;
    const _Float16* Bb = Bt;
    if (EPI == 1) {
        Ab = A  + (size_t)batch * (NDIM * DDIM);
        Bb = Bt + (size_t)batch * (NDIM * DDIM);
    }

    // staging decomposition: per wave-issue, 64 lanes x 16B = 8 rows of 64 fp16.
    // XOR swizzle: lane (lr, lc) fetches logical k-chunk lc^lr so that physical
    // chunk slot lc (pinned by global_load_lds) holds logical chunk (lc^lr).
    const int lr = lane >> 3;                  // row within 8-row chunk (0..7)
    const int lc = lane & 7;                   // physical 16B slot within row
    const int lk = ((lc ^ lr) * 8);            // logical fp16 col offset to fetch

    const int quad = lane >> 4;       // 0..3
    const int l16  = lane & 15;

    f32x4 acc[2][8];
#pragma unroll
    for (int i = 0; i < 2; ++i)
#pragma unroll
        for (int j = 0; j < 8; ++j)
            acc[i][j] = (f32x4){0.f, 0.f, 0.f, 0.f};

    for (int k0 = 0; k0 < DDIM; k0 += 64) {
        // ---- stage A,B tiles: 16 wave-issues each of 1KB; wave w owns chunks w*4..w*4+3
#pragma unroll
        for (int t = 0; t < 4; ++t) {
            int chunk = wv * 4 + t;            // 0..15
            int row   = chunk * 8 + lr;        // 0..127
            gl_lds16(Ab + (size_t)(m0 + row) * DDIM + k0 + lk, &As[chunk * 512]);
            gl_lds16(Bb + (size_t)(n0 + row) * DDIM + k0 + lk, &Bs[chunk * 512]);
        }
        __syncthreads();   // drains vmcnt (global_load_lds) + lgkm

        // ---- compute: 2 K-steps of 32. All fragment rows are ≡ l16 (mod 8),
        // so one swizzled chunk offset pa serves both A and B reads.
#pragma unroll
        for (int kkc = 0; kkc < 8; kkc += 4) {     // kkc = k-chunk base (0 or 4)
            const int pa = (((kkc + quad) ^ (l16 & 7)) * 8);
            f16x8 a0 = *(const f16x8*)&As[(wv * 32 +      l16) * 64 + pa];
            f16x8 a1 = *(const f16x8*)&As[(wv * 32 + 16 + l16) * 64 + pa];
#pragma unroll
            for (int nt = 0; nt < 8; ++nt) {
                f16x8 b = *(const f16x8*)&Bs[(nt * 16 + l16) * 64 + pa];
                acc[0][nt] = __builtin_amdgcn_mfma_f32_16x16x32_f16(a0, b, acc[0][nt], 0, 0, 0);
                acc[1][nt] = __builtin_amdgcn_mfma_f32_16x16x32_f16(a1, b, acc[1][nt], 0, 0, 0);
            }
        }
        __syncthreads();
    }

    // ---- epilogue. C/D layout: col = lane&15, row = quad*4 + reg (m89/m91-verified)
    float bias = (EPI == 1) ? bias_ptr[0] : 0.f;
#pragma unroll
    for (int mt = 0; mt < 2; ++mt) {
#pragma unroll
        for (int nt = 0; nt < 8; ++nt) {
#pragma unroll
            for (int r = 0; r < 4; ++r) {
                int gi = m0 + wv * 32 + mt * 16 + quad * 4 + r;
                int gj = n0 + nt * 16 + l16;
                float v = acc[mt][nt][r];
                if (EPI == 0) {
                    Yout[(size_t)gi * DDIM + gj] = (_Float16)v;
                } else {
                    v += bias;
                    if (gi == gj) v = 0.f;
                    Sout[((size_t)batch * NDIM + gi) * NDIM + gj] = v;
                }
            }
        }
    }
}

extern "C" void kernel_launch(void* const* d_in, const int* in_sizes, int n_in,
                              void* d_out, int out_size, void* d_ws, size_t ws_size,
                              hipStream_t stream) {
    const float* X  = (const float*)d_in[0];   // (32, 512, 512) fp32
    const float* W  = (const float*)d_in[1];   // (512, 512) fp32
    const float* bp = (const float*)d_in[2];   // scalar fp32
    float* out = (float*)d_out;                // (32, 512, 512) fp32

    // workspace layout (fp16): Xh[8388608] | Wt[262144] | Y[8388608]  = 34,078,720 B
    _Float16* Xh = (_Float16*)d_ws;
    _Float16* Wt = Xh + XELEMS;
    _Float16* Y  = Wt + WELEMS;

    // pass 0: dtype conversion + W transpose (merged: 8192 convert + 256 transpose blocks)
    prep<<<XELEMS / 4 / 256 + 256, 256, 0, stream>>>((const float4*)X, (f16x4v*)Xh, W, Wt);

    // pass 1: Y = Xflat(16384x512) @ Wt^T   -> fp16 Y
    gemm_bt<0><<<dim3(4, 128, 1), 256, 0, stream>>>(Xh, Wt, Y, nullptr, nullptr);

    // pass 2: S_b = Y_b(512x512) @ X_b^T  + bias, diag=0 -> fp32 out
    gemm_bt<1><<<dim3(4, 4, BATCH), 256, 0, stream>>>(Y, Xh, nullptr, out, bp);

    (void)in_sizes; (void)n_in; (void)out_size; (void)ws_size;
}

// Round 3
// 115.399 us; speedup vs baseline: 1.0744x; 1.0363x over previous
//
#include <hip/hip_runtime.h>
#include <stdint.h>

// Problem constants (fixed by setup_inputs): B=32, N=512, D=512
#define BATCH 32
#define NDIM 512
#define DDIM 512
#define XELEMS (BATCH * NDIM * DDIM)   // 8388608
#define WELEMS (DDIM * DDIM)           // 262144
#define KITERS (DDIM / 64)             // 8

typedef _Float16 f16x8 __attribute__((ext_vector_type(8)));
typedef _Float16 f16x4v __attribute__((ext_vector_type(4)));
typedef float f32x4 __attribute__((ext_vector_type(4)));

// --- async global -> LDS, 16 bytes per lane (global_load_lds_dwordx4) ---
// LDS dest is wave-uniform base + lane*16 (guide §5 caveat).
__device__ __forceinline__ void gl_lds16(const _Float16* g, _Float16* l) {
    __builtin_amdgcn_global_load_lds(
        (const __attribute__((address_space(1))) unsigned int*)(g),
        (__attribute__((address_space(3))) unsigned int*)(l),
        16, 0, 0);
}

// ---------------- pass 0: X fp32->fp16 convert  +  W fp32->fp16 transpose ----------
__global__ __launch_bounds__(256) void prep(const float4* __restrict__ X4,
                                            f16x4v* __restrict__ Xh4,
                                            const float* __restrict__ W,
                                            _Float16* __restrict__ Wt) {
    __shared__ float tile[32][33];
    int bid = blockIdx.x;
    if (bid < XELEMS / 4 / 256) {
        int i = bid * 256 + threadIdx.x;
        float4 v = X4[i];
        f16x4v o;
        o.x = (_Float16)v.x;
        o.y = (_Float16)v.y;
        o.z = (_Float16)v.z;
        o.w = (_Float16)v.w;
        Xh4[i] = o;
    } else {
        int t = bid - XELEMS / 4 / 256;   // 0..255
        int bx = t & 15;                  // e-tile
        int by = t >> 4;                  // d-tile
        int tx = threadIdx.x & 31;
        int ty = threadIdx.x >> 5;        // 0..7
        for (int r = ty; r < 32; r += 8)
            tile[r][tx] = W[(by * 32 + r) * DDIM + bx * 32 + tx];
        __syncthreads();
        for (int r = ty; r < 32; r += 8)
            Wt[(size_t)(bx * 32 + r) * DDIM + by * 32 + tx] = (_Float16)tile[tx][r];
    }
}

// ---------------- GEMM: C = A @ Bt^T, 128x128 tile, BK=64, double-buffered LDS ------
// Pipeline per iter: barrier (drains stage(it), had a full compute phase to land) ->
// issue stage(it+1) into buf^1 -> compute(it) from buf^0. HBM pull overlaps MFMA.
// XOR-swizzled LDS k-chunks (c ^ (r&7)) keep fragment reads 2-way (free, m136).
// XCD-affine flat-grid decode so blocks sharing operand rows land on one XCD (L2 dedup).
// EPI==0: Y = Xflat @ Wt^T (fp16 out).  EPI==1: S_b = Y_b @ Xh_b^T + bias, diag=0.
template <int EPI>
__global__ __launch_bounds__(256) void gemm_bt(const _Float16* __restrict__ A,
                                               const _Float16* __restrict__ Bt,
                                               _Float16* __restrict__ Yout,
                                               float* __restrict__ Sout,
                                               const float* __restrict__ bias_ptr) {
    __shared__ __align__(16) _Float16 As[2][128 * 64];
    __shared__ __align__(16) _Float16 Bs[2][128 * 64];

    const int tid  = threadIdx.x;
    const int lane = tid & 63;
    const int wv   = tid >> 6;        // 0..3

    // --- XCD-affine decode (XCD ~ blockIdx % 8) ---
    int m0, n0, batch;
    if (EPI == 0) {
        // 512 blocks: n-tile = blk>>7 (0..3), m-tile = blk&127. blk%8 = m%8 ->
        // the 4 n-tiles sharing A rows co-reside on one XCD -> A read once from HBM.
        int blk = blockIdx.x;
        n0 = (blk >> 7) * 128;
        m0 = (blk & 127) * 128;
        batch = 0;
    } else {
        // 512 blocks: batch = blk&31, tile t = blk>>5 (4x4). blk%8 = batch%8 ->
        // all 16 tiles of a batch on one XCD; Y_b + Xh_b (1MB) stay L2-resident.
        int blk = blockIdx.x;
        batch = blk & 31;
        int t = blk >> 5;
        n0 = (t & 3) * 128;
        m0 = (t >> 2) * 128;
    }

    const _Float16* Ab = A;
    const _Float16* Bb = Bt;
    if (EPI == 1) {
        Ab = A  + (size_t)batch * (NDIM * DDIM);
        Bb = Bt + (size_t)batch * (NDIM * DDIM);
    }

    // staging decomposition: per wave-issue, 64 lanes x 16B = 8 rows of 64 fp16.
    // XOR swizzle: physical chunk slot lc holds logical k-chunk lc^lr.
    const int lr = lane >> 3;                  // row within 8-row chunk (0..7)
    const int lc = lane & 7;                   // physical 16B slot within row
    const int lk = ((lc ^ lr) * 8);            // logical fp16 col offset to fetch

    // per-wave global row bases (k0 added per iter)
    const _Float16* ga[4];
    const _Float16* gb[4];
#pragma unroll
    for (int t = 0; t < 4; ++t) {
        int chunk = wv * 4 + t;
        int row   = chunk * 8 + lr;
        ga[t] = Ab + (size_t)(m0 + row) * DDIM + lk;
        gb[t] = Bb + (size_t)(n0 + row) * DDIM + lk;
    }

    const int quad = lane >> 4;       // 0..3
    const int l16  = lane & 15;

    f32x4 acc[2][8];
#pragma unroll
    for (int i = 0; i < 2; ++i)
#pragma unroll
        for (int j = 0; j < 8; ++j)
            acc[i][j] = (f32x4){0.f, 0.f, 0.f, 0.f};

    // ---- prologue: stage tile 0 into buf 0
#pragma unroll
    for (int t = 0; t < 4; ++t) {
        int chunk = wv * 4 + t;
        gl_lds16(ga[t], &As[0][chunk * 512]);
        gl_lds16(gb[t], &Bs[0][chunk * 512]);
    }

    for (int it = 0; it < KITERS; ++it) {
        const int buf = it & 1;
        __syncthreads();   // drains stage(it) vmcnt; fences buf^1 vs compute(it-1)

        // ---- prefetch tile it+1 into the other buffer (overlaps compute below)
        if (it + 1 < KITERS) {
            const int k1 = (it + 1) * 64;
#pragma unroll
            for (int t = 0; t < 4; ++t) {
                int chunk = wv * 4 + t;
                gl_lds16(ga[t] + k1, &As[buf ^ 1][chunk * 512]);
                gl_lds16(gb[t] + k1, &Bs[buf ^ 1][chunk * 512]);
            }
        }

        // ---- compute tile it: 2 K-steps of 32. All fragment rows ≡ l16 (mod 8),
        // so one swizzled chunk offset pa serves both A and B reads.
#pragma unroll
        for (int kkc = 0; kkc < 8; kkc += 4) {     // k-chunk base (0 or 4)
            const int pa = (((kkc + quad) ^ (l16 & 7)) * 8);
            f16x8 a0 = *(const f16x8*)&As[buf][(wv * 32 +      l16) * 64 + pa];
            f16x8 a1 = *(const f16x8*)&As[buf][(wv * 32 + 16 + l16) * 64 + pa];
#pragma unroll
            for (int nt = 0; nt < 8; ++nt) {
                f16x8 b = *(const f16x8*)&Bs[buf][(nt * 16 + l16) * 64 + pa];
                acc[0][nt] = __builtin_amdgcn_mfma_f32_16x16x32_f16(a0, b, acc[0][nt], 0, 0, 0);
                acc[1][nt] = __builtin_amdgcn_mfma_f32_16x16x32_f16(a1, b, acc[1][nt], 0, 0, 0);
            }
        }
    }

    // ---- epilogue. C/D layout: col = lane&15, row = quad*4 + reg (m89/m91-verified)
    float bias = (EPI == 1) ? bias_ptr[0] : 0.f;
#pragma unroll
    for (int mt = 0; mt < 2; ++mt) {
#pragma unroll
        for (int nt = 0; nt < 8; ++nt) {
#pragma unroll
            for (int r = 0; r < 4; ++r) {
                int gi = m0 + wv * 32 + mt * 16 + quad * 4 + r;
                int gj = n0 + nt * 16 + l16;
                float v = acc[mt][nt][r];
                if (EPI == 0) {
                    Yout[(size_t)gi * DDIM + gj] = (_Float16)v;
                } else {
                    v += bias;
                    if (gi == gj) v = 0.f;
                    Sout[((size_t)batch * NDIM + gi) * NDIM + gj] = v;
                }
            }
        }
    }
}

extern "C" void kernel_launch(void* const* d_in, const int* in_sizes, int n_in,
                              void* d_out, int out_size, void* d_ws, size_t ws_size,
                              hipStream_t stream) {
    const float* X  = (const float*)d_in[0];   // (32, 512, 512) fp32
    const float* W  = (const float*)d_in[1];   // (512, 512) fp32
    const float* bp = (const float*)d_in[2];   // scalar fp32
    float* out = (float*)d_out;                // (32, 512, 512) fp32

    // workspace layout (fp16): Xh[8388608] | Wt[262144] | Y[8388608]
    _Float16* Xh = (_Float16*)d_ws;
    _Float16* Wt = Xh + XELEMS;
    _Float16* Y  = Wt + WELEMS;

    // pass 0: dtype conversion + W transpose
    prep<<<XELEMS / 4 / 256 + 256, 256, 0, stream>>>((const float4*)X, (f16x4v*)Xh, W, Wt);

    // pass 1: Y = Xflat(16384x512) @ Wt^T   -> fp16 Y   (flat grid, XCD-affine decode)
    gemm_bt<0><<<512, 256, 0, stream>>>(Xh, Wt, Y, nullptr, nullptr);

    // pass 2: S_b = Y_b(512x512) @ Xh_b^T + bias, diag=0 -> fp32 out
    gemm_bt<1><<<512, 256, 0, stream>>>(Y, Xh, nullptr, out, bp);

    (void)in_sizes; (void)n_in; (void)out_size; (void)ws_size;
}

// Round 4
// 112.822 us; speedup vs baseline: 1.0990x; 1.0228x over previous
//
#include <hip/hip_runtime.h>
#include <stdint.h>

// Problem constants (fixed by setup_inputs): B=32, N=512, D=512
#define BATCH 32
#define NDIM 512
#define DDIM 512
#define XELEMS (BATCH * NDIM * DDIM)   // 8388608
#define WELEMS (DDIM * DDIM)           // 262144
#define KITERS (DDIM / 64)             // 8

typedef _Float16 f16x8 __attribute__((ext_vector_type(8)));
typedef _Float16 f16x4v __attribute__((ext_vector_type(4)));
typedef float f32x4 __attribute__((ext_vector_type(4)));

// --- async global -> LDS, 16 bytes per lane (global_load_lds_dwordx4) ---
__device__ __forceinline__ void gl_lds16(const _Float16* g, _Float16* l) {
    __builtin_amdgcn_global_load_lds(
        (const __attribute__((address_space(1))) unsigned int*)(g),
        (__attribute__((address_space(3))) unsigned int*)(l),
        16, 0, 0);
}

// ---------------- pass 0: X fp32->fp16 convert  +  W fp32->fp16 transpose ----------
__global__ __launch_bounds__(256) void prep(const float4* __restrict__ X4,
                                            f16x4v* __restrict__ Xh4,
                                            const float* __restrict__ W,
                                            _Float16* __restrict__ Wt) {
    __shared__ float tile[32][33];
    int bid = blockIdx.x;
    if (bid < XELEMS / 4 / 256) {
        int i = bid * 256 + threadIdx.x;
        float4 v = X4[i];
        f16x4v o;
        o.x = (_Float16)v.x;
        o.y = (_Float16)v.y;
        o.z = (_Float16)v.z;
        o.w = (_Float16)v.w;
        Xh4[i] = o;
    } else {
        int t = bid - XELEMS / 4 / 256;   // 0..255
        int bx = t & 15;                  // e-tile
        int by = t >> 4;                  // d-tile
        int tx = threadIdx.x & 31;
        int ty = threadIdx.x >> 5;        // 0..7
        for (int r = ty; r < 32; r += 8)
            tile[r][tx] = W[(by * 32 + r) * DDIM + bx * 32 + tx];
        __syncthreads();
        for (int r = ty; r < 32; r += 8)
            Wt[(size_t)(bx * 32 + r) * DDIM + by * 32 + tx] = (_Float16)tile[tx][r];
    }
}

// ---------------- GEMM: C = A @ Bt^T, 128x64 tile, BK=64, single-buffered LDS -------
// Grid 1024 -> 4 blocks/CU, 16 waves/CU (2x the 128x128 version) — occupancy is the
// lever this round: R1-R3 showed conflict/dbuf/L2 changes all neutral at 2 blocks/CU.
// m97-style 2-barrier K-loop; inter-block overlap (m114) hides the barrier drains.
// XOR-swizzled LDS k-chunks (c ^ (r&7)): fragment reads fan across all 32 banks.
// EPI==0: Y = Xflat @ Wt^T (fp16 out).  EPI==1: S_b = Y_b @ Xh_b^T + bias, diag=0.
template <int EPI>
__global__ __launch_bounds__(256) void gemm_bt(const _Float16* __restrict__ A,
                                               const _Float16* __restrict__ Bt,
                                               _Float16* __restrict__ Yout,
                                               float* __restrict__ Sout,
                                               const float* __restrict__ bias_ptr) {
    __shared__ __align__(16) _Float16 As[128 * 64];   // 16 KB
    __shared__ __align__(16) _Float16 Bs[64 * 64];    //  8 KB

    const int tid  = threadIdx.x;
    const int lane = tid & 63;
    const int wv   = tid >> 6;        // 0..3

    // --- XCD-affine decode (XCD ~ blockIdx % 8) ---
    int m0, n0, batch;
    if (EPI == 0) {
        // 1024 blocks: n-tile = blk>>7 (0..7), m-tile = blk&127. blk%8 = m%8 ->
        // the 8 n-tiles sharing an A-panel co-reside on one XCD -> HBM-deduped.
        int blk = blockIdx.x;
        n0 = (blk >> 7) * 64;
        m0 = (blk & 127) * 128;
        batch = 0;
    } else {
        // 1024 blocks: batch = blk&31, t = blk>>5: j = t&7, i = t>>3.
        // blk%8 = batch%8 -> batch's Y_b+Xh_b (1MB) pinned to one XCD's L2.
        int blk = blockIdx.x;
        batch = blk & 31;
        int t = blk >> 5;
        n0 = (t & 7) * 64;
        m0 = (t >> 3) * 128;
    }

    const _Float16* Ab = A;
    const _Float16* Bb = Bt;
    if (EPI == 1) {
        Ab = A  + (size_t)batch * (NDIM * DDIM);
        Bb = Bt + (size_t)batch * (NDIM * DDIM);
    }

    // staging: per wave-issue, 64 lanes x 16B = one 8-row x 64-col fp16 chunk.
    // XOR swizzle: physical 16B slot lc holds logical k-chunk lc^lr.
    const int lr = lane >> 3;                  // row within chunk (0..7)
    const int lc = lane & 7;                   // physical 16B slot within row
    const int lk = ((lc ^ lr) * 8);            // logical fp16 col offset to fetch

    // per-wave global row bases: A has 16 chunks (wave owns 4), B has 8 (wave owns 2)
    const _Float16* ga[4];
    const _Float16* gb[2];
#pragma unroll
    for (int t = 0; t < 4; ++t) {
        int chunk = wv * 4 + t;
        ga[t] = Ab + (size_t)(m0 + chunk * 8 + lr) * DDIM + lk;
    }
#pragma unroll
    for (int t = 0; t < 2; ++t) {
        int chunk = wv * 2 + t;
        gb[t] = Bb + (size_t)(n0 + chunk * 8 + lr) * DDIM + lk;
    }

    const int quad = lane >> 4;       // 0..3
    const int l16  = lane & 15;

    f32x4 acc[2][4];
#pragma unroll
    for (int i = 0; i < 2; ++i)
#pragma unroll
        for (int j = 0; j < 4; ++j)
            acc[i][j] = (f32x4){0.f, 0.f, 0.f, 0.f};

    for (int it = 0; it < KITERS; ++it) {
        const int k0 = it * 64;
        // ---- stage A,B tiles
#pragma unroll
        for (int t = 0; t < 4; ++t)
            gl_lds16(ga[t] + k0, &As[(wv * 4 + t) * 512]);
#pragma unroll
        for (int t = 0; t < 2; ++t)
            gl_lds16(gb[t] + k0, &Bs[(wv * 2 + t) * 512]);
        __syncthreads();   // drains vmcnt; inter-block overlap hides this at 4 blk/CU

        // ---- compute: 2 K-steps of 32. All fragment rows ≡ l16 (mod 8),
        // so one swizzled chunk offset pa serves both A and B reads.
#pragma unroll
        for (int kkc = 0; kkc < 8; kkc += 4) {     // k-chunk base (0 or 4)
            const int pa = (((kkc + quad) ^ (l16 & 7)) * 8);
            f16x8 a0 = *(const f16x8*)&As[(wv * 32 +      l16) * 64 + pa];
            f16x8 a1 = *(const f16x8*)&As[(wv * 32 + 16 + l16) * 64 + pa];
#pragma unroll
            for (int nt = 0; nt < 4; ++nt) {
                f16x8 b = *(const f16x8*)&Bs[(nt * 16 + l16) * 64 + pa];
                acc[0][nt] = __builtin_amdgcn_mfma_f32_16x16x32_f16(a0, b, acc[0][nt], 0, 0, 0);
                acc[1][nt] = __builtin_amdgcn_mfma_f32_16x16x32_f16(a1, b, acc[1][nt], 0, 0, 0);
            }
        }
        __syncthreads();
    }

    // ---- epilogue. C/D layout: col = lane&15, row = quad*4 + reg (m89/m91-verified)
    float bias = (EPI == 1) ? bias_ptr[0] : 0.f;
#pragma unroll
    for (int mt = 0; mt < 2; ++mt) {
#pragma unroll
        for (int nt = 0; nt < 4; ++nt) {
#pragma unroll
            for (int r = 0; r < 4; ++r) {
                int gi = m0 + wv * 32 + mt * 16 + quad * 4 + r;
                int gj = n0 + nt * 16 + l16;
                float v = acc[mt][nt][r];
                if (EPI == 0) {
                    Yout[(size_t)gi * DDIM + gj] = (_Float16)v;
                } else {
                    v += bias;
                    if (gi == gj) v = 0.f;
                    Sout[((size_t)batch * NDIM + gi) * NDIM + gj] = v;
                }
            }
        }
    }
}

extern "C" void kernel_launch(void* const* d_in, const int* in_sizes, int n_in,
                              void* d_out, int out_size, void* d_ws, size_t ws_size,
                              hipStream_t stream) {
    const float* X  = (const float*)d_in[0];   // (32, 512, 512) fp32
    const float* W  = (const float*)d_in[1];   // (512, 512) fp32
    const float* bp = (const float*)d_in[2];   // scalar fp32
    float* out = (float*)d_out;                // (32, 512, 512) fp32

    // workspace layout (fp16): Xh[8388608] | Wt[262144] | Y[8388608]
    _Float16* Xh = (_Float16*)d_ws;
    _Float16* Wt = Xh + XELEMS;
    _Float16* Y  = Wt + WELEMS;

    // pass 0: dtype conversion + W transpose
    prep<<<XELEMS / 4 / 256 + 256, 256, 0, stream>>>((const float4*)X, (f16x4v*)Xh, W, Wt);

    // pass 1: Y = Xflat(16384x512) @ Wt^T -> fp16 Y   (1024 blocks, 4/CU)
    gemm_bt<0><<<1024, 256, 0, stream>>>(Xh, Wt, Y, nullptr, nullptr);

    // pass 2: S_b = Y_b(512x512) @ Xh_b^T + bias, diag=0 -> fp32 out (1024 blocks)
    gemm_bt<1><<<1024, 256, 0, stream>>>(Y, Xh, nullptr, out, bp);

    (void)in_sizes; (void)n_in; (void)out_size; (void)ws_size;
}